// Round 2
// baseline (967.705 us; speedup 1.0000x reference)
//
#include <hip/hip_runtime.h>
#include <cmath>

// Problem dims (fixed): B=512, T=128, F=256, H=128, 4H=512, M=B*T=65536
#define BB 512
#define TT 128
#define FF 256
#define HH 128
#define GG 512
#define MM 65536

__device__ __forceinline__ float sigmf(float x) { return 1.0f / (1.0f + __expf(-x)); }
__device__ __forceinline__ float tanh_fast(float x) {
    // 1 - 2/(exp(2x)+1); handles +-inf saturation correctly
    return 1.0f - 2.0f / (__expf(2.0f * x) + 1.0f);
}

// ---------------------------------------------------------------------------
// K1: per (b,f) lane over time: mask, deltaX, X_mean, dx, X_new, Sx cumsum,
// c_mask.  grid: B blocks x F threads.
// ---------------------------------------------------------------------------
__global__ __launch_bounds__(256) void k1_preprocess(
    const float* __restrict__ X, const float* __restrict__ X_last,
    const float* __restrict__ W_x, const float* __restrict__ b_x,
    const float* __restrict__ W_attn,
    float* __restrict__ DX, float* __restrict__ SX, float* __restrict__ CM)
{
    const int b = blockIdx.x;
    const int f = threadIdx.x;
    __shared__ float wl[256];               // [wa_x(128) | wa_m(128)]
    wl[f] = W_attn[256 + f];
    __syncthreads();

    const float* xb  = X      + (size_t)b * TT * FF + f;
    const float* xlb = X_last + (size_t)b * TT * FF + f;

    // pass 1: mask bits, sum/count, c_mask
    unsigned long long mb0 = 0ull, mb1 = 0ull;
    float sum = 0.f, cnt = 0.f, cm = 0.f;
    for (int t = 0; t < TT; ++t) {
        float x = xb[t * FF];
        bool m = (x != -1.0f);
        if (m) {
            sum += x; cnt += 1.0f;
            if (t < 64) mb0 |= (1ull << t); else mb1 |= (1ull << (t - 64));
        }
        cm += (m ? 1.0f : 0.0f) * wl[128 + t];
    }
    const float mean = (cnt > 0.f) ? (sum / cnt) : 0.f;
    CM[(size_t)b * FF + f] = cm;

    const float wxd = W_x[(size_t)f * FF + f];
    const float bx  = b_x[f];
    float* dxb = DX + (size_t)b * TT * FF + f;
    float* sxb = SX + (size_t)b * TT * FF + f;

    // pass 2: deltaX, X_new, running cumsum
    float d = 0.f, s = 0.f;
    bool mprev = false;
    for (int t = 0; t < TT; ++t) {
        bool m = (t < 64) ? ((mb0 >> t) & 1ull) : ((mb1 >> (t - 64)) & 1ull);
        if (t > 0) d = mprev ? 1.0f : (d + 1.0f);
        mprev = m;
        dxb[t * FF] = d;
        float x   = xb[t * FF];
        float x0  = m ? x : 0.f;
        float dxv = __expf(-fmaxf(fmaf(d, wxd, bx), 0.f));
        float xl  = xlb[t * FF];
        float xnew = m ? x0 : (dxv * xl + (1.0f - dxv) * mean);
        s += xnew * wl[t];
        sxb[t * FF] = s;
    }
}

// ---------------------------------------------------------------------------
// K2/K4: f32 tiled GEMM.  C[row, col] = A[row,:] . W[col,:] (+ epilogue)
// A: (M,256) row-major.  W: (Ntot,256) row-major.  Tile 64x128, KC=32.
// EPI 0: C = exp(-relu(acc + bias1))       (Dh)
// EPI 1: C = acc + bias1 + bias2           (G)
// ---------------------------------------------------------------------------
template <int EPI>
__global__ __launch_bounds__(256) void gemm_f32(
    const float* __restrict__ A, const float* __restrict__ W,
    const float* __restrict__ bias1, const float* __restrict__ bias2,
    float* __restrict__ C, int Ntot)
{
    __shared__ float Ast[32][68];    // [k][row], padded, 16B-aligned rows
    __shared__ float Bst[32][132];   // [k][col], padded

    const int tid = threadIdx.x;
    const int tx = tid & 31;         // 32 col-groups of 4
    const int ty = tid >> 5;         // 8 row-groups of 8
    const int r0 = blockIdx.x * 64;
    const int c0 = blockIdx.y * 128;

    float acc[8][4];
#pragma unroll
    for (int i = 0; i < 8; ++i)
#pragma unroll
        for (int j = 0; j < 4; ++j) acc[i][j] = 0.f;

    for (int kc = 0; kc < 256; kc += 32) {
#pragma unroll
        for (int p = 0; p < 8; ++p) {
            int e = tid + p * 256;
            Ast[e & 31][e >> 5] = A[(size_t)(r0 + (e >> 5)) * 256 + kc + (e & 31)];
        }
#pragma unroll
        for (int p = 0; p < 16; ++p) {
            int e = tid + p * 256;
            Bst[e & 31][e >> 5] = W[(size_t)(c0 + (e >> 5)) * 256 + kc + (e & 31)];
        }
        __syncthreads();
#pragma unroll
        for (int k = 0; k < 32; ++k) {
            const float4 a0 = *(const float4*)&Ast[k][ty * 8];
            const float4 a1 = *(const float4*)&Ast[k][ty * 8 + 4];
            const float4 bv = *(const float4*)&Bst[k][tx * 4];
            float av[8] = {a0.x, a0.y, a0.z, a0.w, a1.x, a1.y, a1.z, a1.w};
#pragma unroll
            for (int i = 0; i < 8; ++i) {
                acc[i][0] = fmaf(av[i], bv.x, acc[i][0]);
                acc[i][1] = fmaf(av[i], bv.y, acc[i][1]);
                acc[i][2] = fmaf(av[i], bv.z, acc[i][2]);
                acc[i][3] = fmaf(av[i], bv.w, acc[i][3]);
            }
        }
        __syncthreads();
    }

    float b1[4], b2[4];
#pragma unroll
    for (int j = 0; j < 4; ++j) {
        int col = c0 + tx * 4 + j;
        b1[j] = bias1[col];
        b2[j] = (EPI == 1) ? bias2[col] : 0.f;
    }
#pragma unroll
    for (int i = 0; i < 8; ++i) {
        int row = r0 + ty * 8 + i;
        float4 o;
        float v0 = acc[i][0] + b1[0] + b2[0];
        float v1 = acc[i][1] + b1[1] + b2[1];
        float v2 = acc[i][2] + b1[2] + b2[2];
        float v3 = acc[i][3] + b1[3] + b2[3];
        if (EPI == 0) {
            o.x = __expf(-fmaxf(v0, 0.f));
            o.y = __expf(-fmaxf(v1, 0.f));
            o.z = __expf(-fmaxf(v2, 0.f));
            o.w = __expf(-fmaxf(v3, 0.f));
        } else {
            o.x = v0; o.y = v1; o.z = v2; o.w = v3;
        }
        *(float4*)&C[(size_t)row * Ntot + c0 + tx * 4] = o;
    }
}

// ---------------------------------------------------------------------------
// K3: alpha = softmax_f(Sx + c_mask); X_tilde = alpha * X0 -> d_out.
// One wave per (b,t) row, 4 f per lane.  grid: M/4 blocks x 256 threads.
// ---------------------------------------------------------------------------
__global__ __launch_bounds__(256) void k3_softmax(
    const float* __restrict__ SX, const float* __restrict__ CM,
    const float* __restrict__ X, float* __restrict__ Xt)
{
    const int tid  = threadIdx.x;
    const int lane = tid & 63;
    const int w    = tid >> 6;
    const int r    = blockIdx.x * 4 + w;      // bt row
    const int b    = r >> 7;

    const float4 sx = *(const float4*)&SX[(size_t)r * FF + lane * 4];
    const float4 cm = *(const float4*)&CM[(size_t)b * FF + lane * 4];
    float s0 = sx.x + cm.x, s1 = sx.y + cm.y, s2 = sx.z + cm.z, s3 = sx.w + cm.w;

    float mx = fmaxf(fmaxf(s0, s1), fmaxf(s2, s3));
#pragma unroll
    for (int o = 32; o > 0; o >>= 1) mx = fmaxf(mx, __shfl_xor(mx, o));
    float e0 = __expf(s0 - mx), e1 = __expf(s1 - mx);
    float e2 = __expf(s2 - mx), e3 = __expf(s3 - mx);
    float sm = e0 + e1 + e2 + e3;
#pragma unroll
    for (int o = 32; o > 0; o >>= 1) sm += __shfl_xor(sm, o);
    float inv = 1.0f / sm;

    const float4 xv = *(const float4*)&X[(size_t)r * FF + lane * 4];
    float4 o4;
    o4.x = ((xv.x != -1.0f) ? xv.x : 0.f) * e0 * inv;
    o4.y = ((xv.y != -1.0f) ? xv.y : 0.f) * e1 * inv;
    o4.z = ((xv.z != -1.0f) ? xv.z : 0.f) * e2 * inv;
    o4.w = ((xv.w != -1.0f) ? xv.w : 0.f) * e3 * inv;
    *(float4*)&Xt[(size_t)r * FF + lane * 4] = o4;
}

// ---------------------------------------------------------------------------
// K5: sequential LSTM-style recurrence.  256 blocks x 512 threads, 2 batch
// rows per block.  Thread j holds W_hh[j,0:128] in VGPRs; h broadcast via LDS.
// Dh is aliased into the X_enc region of d_out: element (b,t,k) is read in
// phase 1 and overwritten (as X_enc) in phase 3 of the same step by the same
// thread, so the aliasing is safe.
// ---------------------------------------------------------------------------
__global__ __launch_bounds__(512, 2) void k5_recurrence(
    const float* __restrict__ Dh, const float* __restrict__ G,
    const float* __restrict__ W_hh, float* __restrict__ Xenc)
{
    const int tid = threadIdx.x;
    const int b0 = blockIdx.x * 2;

    __shared__ __align__(16) float h_lds[2][128];
    __shared__ float g_lds[2][512];

    float w[128];
    const float* wr = W_hh + (size_t)tid * 128;
#pragma unroll
    for (int k = 0; k < 128; ++k) w[k] = wr[k];

    const int r  = tid >> 7;    // 0..3 (only 0,1 own state)
    const int k0 = tid & 127;
    float h_reg = 0.f, c_reg = 0.f;

    for (int t = 0; t < TT; ++t) {
        if (tid < 256) {
            float hdh = Dh[((size_t)(b0 + r) * TT + t) * HH + k0] * h_reg;
            h_lds[r][k0] = hdh;
        }
        __syncthreads();

        float acc0 = G[((size_t)b0       * TT + t) * GG + tid];
        float acc1 = G[((size_t)(b0 + 1) * TT + t) * GG + tid];
#pragma unroll
        for (int k = 0; k < 128; k += 4) {
            const float4 h0 = *(const float4*)&h_lds[0][k];
            const float4 h1 = *(const float4*)&h_lds[1][k];
            acc0 = fmaf(h0.x, w[k], acc0);
            acc0 = fmaf(h0.y, w[k + 1], acc0);
            acc0 = fmaf(h0.z, w[k + 2], acc0);
            acc0 = fmaf(h0.w, w[k + 3], acc0);
            acc1 = fmaf(h1.x, w[k], acc1);
            acc1 = fmaf(h1.y, w[k + 1], acc1);
            acc1 = fmaf(h1.z, w[k + 2], acc1);
            acc1 = fmaf(h1.w, w[k + 3], acc1);
        }
        g_lds[0][tid] = acc0;
        g_lds[1][tid] = acc1;
        __syncthreads();

        if (tid < 256) {
            float gi = g_lds[r][k0];
            float gf = g_lds[r][k0 + 128];
            float gg = g_lds[r][k0 + 256];
            float go = g_lds[r][k0 + 384];
            c_reg = sigmf(gf) * c_reg + sigmf(gi) * tanh_fast(gg);
            h_reg = sigmf(go) * tanh_fast(c_reg);
            Xenc[((size_t)(b0 + r) * TT + t) * HH + k0] = h_reg;
        }
        __syncthreads();
    }
}

// ---------------------------------------------------------------------------
extern "C" void kernel_launch(void* const* d_in, const int* in_sizes, int n_in,
                              void* d_out, int out_size, void* d_ws, size_t ws_size,
                              hipStream_t stream)
{
    const float* X      = (const float*)d_in[0];
    const float* X_last = (const float*)d_in[1];
    const float* W_x    = (const float*)d_in[2];
    const float* b_x    = (const float*)d_in[3];
    const float* W_h    = (const float*)d_in[4];
    const float* b_h    = (const float*)d_in[5];
    const float* W_ih   = (const float*)d_in[6];
    const float* b_ih   = (const float*)d_in[7];
    const float* W_hh   = (const float*)d_in[8];
    const float* b_hh   = (const float*)d_in[9];
    const float* W_attn = (const float*)d_in[10];

    float* ws = (float*)d_ws;
    // layout (floats):
    //   DX : [0, 16777216)              dead after K2
    //   SX : [16777216, 33554432)       dead after K3
    //   G  : [0, 33554432)              written in K4 (over DX+SX)
    //   CM : [33554432, 33685504)
    float* DX = ws;
    float* SX = ws + (size_t)16777216;
    float* Gb = ws;
    float* CM = ws + (size_t)33554432;

    float* Xt   = (float*)d_out;                       // (B,T,F)
    float* Xenc = (float*)d_out + (size_t)16777216;    // (B,T,H)
    float* DH   = Xenc;                                // aliased (see K5)

    k1_preprocess<<<BB, 256, 0, stream>>>(X, X_last, W_x, b_x, W_attn, DX, SX, CM);
    gemm_f32<0><<<dim3(MM / 64, 1), 256, 0, stream>>>(DX, W_h, b_h, nullptr, DH, HH);
    k3_softmax<<<MM / 4, 256, 0, stream>>>(SX, CM, X, Xt);
    gemm_f32<1><<<dim3(MM / 64, 4), 256, 0, stream>>>(Xt, W_ih, b_ih, b_hh, Gb, GG);
    k5_recurrence<<<BB / 2, 512, 0, stream>>>(DH, Gb, W_hh, Xenc);
}

// Round 6
// 705.639 us; speedup vs baseline: 1.3714x; 1.3714x over previous
//
#include <hip/hip_runtime.h>
#include <hip/hip_bf16.h>
#include <cmath>

// Problem dims (fixed): B=512, T=128, F=256, H=128, 4H=512, M=B*T=65536
#define BB 512
#define TT 128
#define FF 256
#define HH 128
#define GG 512
#define MM 65536

typedef short bf16x8 __attribute__((ext_vector_type(8)));
typedef float f32x4 __attribute__((ext_vector_type(4)));

__device__ __forceinline__ float sigmf(float x) { return 1.0f / (1.0f + __expf(-x)); }
__device__ __forceinline__ float tanh_fast(float x) {
    return 1.0f - 2.0f / (__expf(2.0f * x) + 1.0f);
}
__device__ __forceinline__ short f2bf(float f) {
    __hip_bfloat16 h = __float2bfloat16(f);   // round-to-nearest-even
    return *reinterpret_cast<short*>(&h);
}
__device__ __forceinline__ float bf2f(short s) {
    unsigned int u = ((unsigned int)(unsigned short)s) << 16;
    return __uint_as_float(u);
}
__device__ __forceinline__ bf16x8 cvt8(const float* p) {
    bf16x8 r;
#pragma unroll
    for (int i = 0; i < 8; ++i) r[i] = f2bf(p[i]);
    return r;
}

// ---------------------------------------------------------------------------
// K1: per (b,f) lane over time: mask, deltaX, X_mean, dx, X_new, Sx cumsum,
// c_mask.  grid: B blocks x F threads.  (unchanged)
// ---------------------------------------------------------------------------
__global__ __launch_bounds__(256) void k1_preprocess(
    const float* __restrict__ X, const float* __restrict__ X_last,
    const float* __restrict__ W_x, const float* __restrict__ b_x,
    const float* __restrict__ W_attn,
    float* __restrict__ DX, float* __restrict__ SX, float* __restrict__ CM)
{
    const int b = blockIdx.x;
    const int f = threadIdx.x;
    __shared__ float wl[256];               // [wa_x(128) | wa_m(128)]
    wl[f] = W_attn[256 + f];
    __syncthreads();

    const float* xb  = X      + (size_t)b * TT * FF + f;
    const float* xlb = X_last + (size_t)b * TT * FF + f;

    unsigned long long mb0 = 0ull, mb1 = 0ull;
    float sum = 0.f, cnt = 0.f, cm = 0.f;
    for (int t = 0; t < TT; ++t) {
        float x = xb[t * FF];
        bool m = (x != -1.0f);
        if (m) {
            sum += x; cnt += 1.0f;
            if (t < 64) mb0 |= (1ull << t); else mb1 |= (1ull << (t - 64));
        }
        cm += (m ? 1.0f : 0.0f) * wl[128 + t];
    }
    const float mean = (cnt > 0.f) ? (sum / cnt) : 0.f;
    CM[(size_t)b * FF + f] = cm;

    const float wxd = W_x[(size_t)f * FF + f];
    const float bx  = b_x[f];
    float* dxb = DX + (size_t)b * TT * FF + f;
    float* sxb = SX + (size_t)b * TT * FF + f;

    float d = 0.f, s = 0.f;
    bool mprev = false;
    for (int t = 0; t < TT; ++t) {
        bool m = (t < 64) ? ((mb0 >> t) & 1ull) : ((mb1 >> (t - 64)) & 1ull);
        if (t > 0) d = mprev ? 1.0f : (d + 1.0f);
        mprev = m;
        dxb[t * FF] = d;
        float x   = xb[t * FF];
        float x0  = m ? x : 0.f;
        float dxv = __expf(-fmaxf(fmaf(d, wxd, bx), 0.f));
        float xl  = xlb[t * FF];
        float xnew = m ? x0 : (dxv * xl + (1.0f - dxv) * mean);
        s += xnew * wl[t];
        sxb[t * FF] = s;
    }
}

// ---------------------------------------------------------------------------
// K2: f32 tiled GEMM (Dh).  C = exp(-relu(A.W^T + bias1)).  (unchanged)
// ---------------------------------------------------------------------------
__global__ __launch_bounds__(256) void gemm_f32_dh(
    const float* __restrict__ A, const float* __restrict__ W,
    const float* __restrict__ bias1, float* __restrict__ C, int Ntot)
{
    __shared__ float Ast[32][68];
    __shared__ float Bst[32][132];

    const int tid = threadIdx.x;
    const int tx = tid & 31;
    const int ty = tid >> 5;
    const int r0 = blockIdx.x * 64;
    const int c0 = blockIdx.y * 128;

    float acc[8][4];
#pragma unroll
    for (int i = 0; i < 8; ++i)
#pragma unroll
        for (int j = 0; j < 4; ++j) acc[i][j] = 0.f;

    for (int kc = 0; kc < 256; kc += 32) {
#pragma unroll
        for (int p = 0; p < 8; ++p) {
            int e = tid + p * 256;
            Ast[e & 31][e >> 5] = A[(size_t)(r0 + (e >> 5)) * 256 + kc + (e & 31)];
        }
#pragma unroll
        for (int p = 0; p < 16; ++p) {
            int e = tid + p * 256;
            Bst[e & 31][e >> 5] = W[(size_t)(c0 + (e >> 5)) * 256 + kc + (e & 31)];
        }
        __syncthreads();
#pragma unroll
        for (int k = 0; k < 32; ++k) {
            const float4 a0 = *(const float4*)&Ast[k][ty * 8];
            const float4 a1 = *(const float4*)&Ast[k][ty * 8 + 4];
            const float4 bv = *(const float4*)&Bst[k][tx * 4];
            float av[8] = {a0.x, a0.y, a0.z, a0.w, a1.x, a1.y, a1.z, a1.w};
#pragma unroll
            for (int i = 0; i < 8; ++i) {
                acc[i][0] = fmaf(av[i], bv.x, acc[i][0]);
                acc[i][1] = fmaf(av[i], bv.y, acc[i][1]);
                acc[i][2] = fmaf(av[i], bv.z, acc[i][2]);
                acc[i][3] = fmaf(av[i], bv.w, acc[i][3]);
            }
        }
        __syncthreads();
    }

    float b1[4];
#pragma unroll
    for (int j = 0; j < 4; ++j) b1[j] = bias1[c0 + tx * 4 + j];
#pragma unroll
    for (int i = 0; i < 8; ++i) {
        int row = r0 + ty * 8 + i;
        float4 o;
        o.x = __expf(-fmaxf(acc[i][0] + b1[0], 0.f));
        o.y = __expf(-fmaxf(acc[i][1] + b1[1], 0.f));
        o.z = __expf(-fmaxf(acc[i][2] + b1[2], 0.f));
        o.w = __expf(-fmaxf(acc[i][3] + b1[3], 0.f));
        *(float4*)&C[(size_t)row * Ntot + c0 + tx * 4] = o;
    }
}

// ---------------------------------------------------------------------------
// K3: alpha = softmax_f(Sx + c_mask); X_tilde = alpha * X0.  (unchanged)
// ---------------------------------------------------------------------------
__global__ __launch_bounds__(256) void k3_softmax(
    const float* __restrict__ SX, const float* __restrict__ CM,
    const float* __restrict__ X, float* __restrict__ Xt)
{
    const int tid  = threadIdx.x;
    const int lane = tid & 63;
    const int w    = tid >> 6;
    const int r    = blockIdx.x * 4 + w;
    const int b    = r >> 7;

    const float4 sx = *(const float4*)&SX[(size_t)r * FF + lane * 4];
    const float4 cm = *(const float4*)&CM[(size_t)b * FF + lane * 4];
    float s0 = sx.x + cm.x, s1 = sx.y + cm.y, s2 = sx.z + cm.z, s3 = sx.w + cm.w;

    float mx = fmaxf(fmaxf(s0, s1), fmaxf(s2, s3));
#pragma unroll
    for (int o = 32; o > 0; o >>= 1) mx = fmaxf(mx, __shfl_xor(mx, o));
    float e0 = __expf(s0 - mx), e1 = __expf(s1 - mx);
    float e2 = __expf(s2 - mx), e3 = __expf(s3 - mx);
    float sm = e0 + e1 + e2 + e3;
#pragma unroll
    for (int o = 32; o > 0; o >>= 1) sm += __shfl_xor(sm, o);
    float inv = 1.0f / sm;

    const float4 xv = *(const float4*)&X[(size_t)r * FF + lane * 4];
    float4 o4;
    o4.x = ((xv.x != -1.0f) ? xv.x : 0.f) * e0 * inv;
    o4.y = ((xv.y != -1.0f) ? xv.y : 0.f) * e1 * inv;
    o4.z = ((xv.z != -1.0f) ? xv.z : 0.f) * e2 * inv;
    o4.w = ((xv.w != -1.0f) ? xv.w : 0.f) * e3 * inv;
    *(float4*)&Xt[(size_t)r * FF + lane * 4] = o4;
}

// ---------------------------------------------------------------------------
// K4: bf16 MFMA GEMM.  G = Xt(f32->bf16) @ W_ih^T(f32->bf16) + b_ih + b_hh.
// BM=128, BN=128, BK=64.  256 threads (4 waves, 2x2 wave grid, 64x64/wave).
// Reg-staged f32->bf16 conversion; XOR-swizzled LDS (write & read both
// swizzled; no global_load_lds -> rule-21 consistent).
// ---------------------------------------------------------------------------
__global__ __launch_bounds__(256) void k4_gemm_bf16(
    const float* __restrict__ A,      // Xt (M,256) f32
    const float* __restrict__ W,      // W_ih (512,256) f32
    const float* __restrict__ bias1,  // b_ih
    const float* __restrict__ bias2,  // b_hh
    float* __restrict__ C)            // G (M,512) f32
{
    __shared__ short As[128 * 64];    // 16KB, bf16, swizzled rows of 128B
    __shared__ short Bs[128 * 64];    // 16KB

    const int tid  = threadIdx.x;
    const int lane = tid & 63;
    const int wave = tid >> 6;
    const int wm = wave >> 1, wn = wave & 1;
    const int r0 = blockIdx.x * 128;
    const int c0 = blockIdx.y * 128;

    f32x4 acc[4][4] = {};

    for (int kc = 0; kc < 256; kc += 64) {
#pragma unroll
        for (int i = 0; i < 4; ++i) {
            int slot = i * 256 + tid;          // 1024 slots = 128 rows x 8 kgroups
            int row = slot >> 3, kg = slot & 7;
            int byte = (row * 128 + kg * 16) ^ ((row & 7) << 4);
            float tmp[8];
            *(float4*)&tmp[0] = *(const float4*)&A[(size_t)(r0 + row) * 256 + kc + kg * 8];
            *(float4*)&tmp[4] = *(const float4*)&A[(size_t)(r0 + row) * 256 + kc + kg * 8 + 4];
            *(bf16x8*)((char*)As + byte) = cvt8(tmp);
            *(float4*)&tmp[0] = *(const float4*)&W[(size_t)(c0 + row) * 256 + kc + kg * 8];
            *(float4*)&tmp[4] = *(const float4*)&W[(size_t)(c0 + row) * 256 + kc + kg * 8 + 4];
            *(bf16x8*)((char*)Bs + byte) = cvt8(tmp);
        }
        __syncthreads();

#pragma unroll
        for (int ks = 0; ks < 2; ++ks) {
            bf16x8 af[4], bw[4];
#pragma unroll
            for (int mf = 0; mf < 4; ++mf) {
                int row = wm * 64 + mf * 16 + (lane & 15);
                int byte = (row * 128 + ks * 64 + (lane >> 4) * 16) ^ ((row & 7) << 4);
                af[mf] = *(const bf16x8*)((const char*)As + byte);
            }
#pragma unroll
            for (int nf = 0; nf < 4; ++nf) {
                int row = wn * 64 + nf * 16 + (lane & 15);
                int byte = (row * 128 + ks * 64 + (lane >> 4) * 16) ^ ((row & 7) << 4);
                bw[nf] = *(const bf16x8*)((const char*)Bs + byte);
            }
#pragma unroll
            for (int mf = 0; mf < 4; ++mf)
#pragma unroll
                for (int nf = 0; nf < 4; ++nf)
                    acc[mf][nf] = __builtin_amdgcn_mfma_f32_16x16x32_bf16(
                        af[mf], bw[nf], acc[mf][nf], 0, 0, 0);
        }
        __syncthreads();
    }

    float bsum[4];
#pragma unroll
    for (int nf = 0; nf < 4; ++nf) {
        int col = c0 + wn * 64 + nf * 16 + (lane & 15);
        bsum[nf] = bias1[col] + bias2[col];
    }
#pragma unroll
    for (int mf = 0; mf < 4; ++mf)
#pragma unroll
        for (int nf = 0; nf < 4; ++nf) {
            int col = c0 + wn * 64 + nf * 16 + (lane & 15);
#pragma unroll
            for (int reg = 0; reg < 4; ++reg) {
                int row = r0 + wm * 64 + mf * 16 + (lane >> 4) * 4 + reg;
                C[(size_t)row * GG + col] = acc[mf][nf][reg] + bsum[nf];
            }
        }
}

// ---------------------------------------------------------------------------
// K5: sequential recurrence via MFMA.  256 blocks x 512 threads (8 waves),
// 2 batch rows/block.  W_hh held in VGPRs as bf16 B-fragments (16/wave).
// h split hi+lo (2 bf16 MFMA passes -> ~f32 accuracy vs W_hh-bf16 only).
// Wave w owns gates q*128 + 16w + lane for q=0..3 -> in-wave epilogue.
// One barrier/step; double-buffered LDS h; G/Dh prefetched one step ahead.
// Dh aliased into Xenc region of d_out (loads run >=1 row ahead of stores,
// same thread per element -> safe).
// ---------------------------------------------------------------------------
__global__ __launch_bounds__(512) void k5_recurrence_mfma(
    const float* __restrict__ Dh, const float* __restrict__ G,
    const float* __restrict__ W_hh, float* __restrict__ Xenc)
{
    __shared__ short hbuf[2][2][2][128];   // [buf][split hi/lo][row][k] bf16
    const int tid  = threadIdx.x;
    const int lane = tid & 63;
    const int w    = tid >> 6;             // wave 0..7
    const int b0   = blockIdx.x * 2;
    const int l    = lane & 15;
    const bool act = (lane < 16);

    // one-time: load W_hh fragments -> bf16 VGPRs.  frag (q,ks):
    // B[k][col]: col = q*128 + 16w + (lane&15), k = ks*32 + (lane>>4)*8 + j
    bf16x8 wf[4][4];
#pragma unroll
    for (int q = 0; q < 4; ++q)
#pragma unroll
        for (int ks = 0; ks < 4; ++ks) {
            int gate = q * 128 + w * 16 + (lane & 15);
            const float* src = &W_hh[(size_t)gate * HH + ks * 32 + (lane >> 4) * 8];
            float tmp[8];
            *(float4*)&tmp[0] = *(const float4*)&src[0];
            *(float4*)&tmp[4] = *(const float4*)&src[4];
            wf[q][ks] = cvt8(tmp);
        }

    // zero h buffers
    for (int i = tid; i < 2 * 2 * 2 * 128; i += 512) ((short*)hbuf)[i] = 0;

    float cst0 = 0.f, cst1 = 0.f;
    float gnxt[2][4], dhnxt[2];
    if (act) {
#pragma unroll
        for (int r = 0; r < 2; ++r) {
#pragma unroll
            for (int q = 0; q < 4; ++q)
                gnxt[r][q] = G[((size_t)(b0 + r) * TT + 0) * GG + q * 128 + w * 16 + l];
            dhnxt[r] = Dh[((size_t)(b0 + r) * TT + 1) * HH + w * 16 + l];
        }
    }

    for (int t = 0; t < TT; ++t) {
        __syncthreads();                    // orders prev-step h writes vs reads
        const int rb = t & 1;
        f32x4 acc[4] = {};
#pragma unroll
        for (int s = 0; s < 2; ++s) {
#pragma unroll
            for (int ks = 0; ks < 4; ++ks) {
                // A[row][k]: row = lane&15 (maps to h row (lane&1)), k-slice by lane>>4
                const bf16x8 af = *(const bf16x8*)&hbuf[rb][s][lane & 1][ks * 32 + (lane >> 4) * 8];
#pragma unroll
                for (int q = 0; q < 4; ++q)
                    acc[q] = __builtin_amdgcn_mfma_f32_16x16x32_bf16(af, wf[q][ks], acc[q], 0, 0, 0);
            }
        }

        if (act) {
            // consume prefetched values, then prefetch for next step
            float gc[2][4], dc[2];
#pragma unroll
            for (int r = 0; r < 2; ++r) {
#pragma unroll
                for (int q = 0; q < 4; ++q) gc[r][q] = gnxt[r][q];
                dc[r] = dhnxt[r];
            }
            const int tn  = (t + 1 < TT) ? (t + 1) : (TT - 1);
            const int tn2 = (t + 2 < TT) ? (t + 2) : (TT - 1);
#pragma unroll
            for (int r = 0; r < 2; ++r) {
#pragma unroll
                for (int q = 0; q < 4; ++q)
                    gnxt[r][q] = G[((size_t)(b0 + r) * TT + tn) * GG + q * 128 + w * 16 + l];
                dhnxt[r] = Dh[((size_t)(b0 + r) * TT + tn2) * HH + w * 16 + l];
            }

            // gate epilogue: lanes 0-15 hold C rows 0 (reg0) and 1 (reg1)
#pragma unroll
            for (int r = 0; r < 2; ++r) {
                float gi = acc[0][r] + gc[r][0];
                float gf = acc[1][r] + gc[r][1];
                float gg = acc[2][r] + gc[r][2];
                float go = acc[3][r] + gc[r][3];
                float cprev = r ? cst1 : cst0;
                float c = sigmf(gf) * cprev + sigmf(gi) * tanh_fast(gg);
                if (r) cst1 = c; else cst0 = c;
                float h = sigmf(go) * tanh_fast(c);
                Xenc[((size_t)(b0 + r) * TT + t) * HH + w * 16 + l] = h;
                float hp = dc[r] * h;
                short hi = f2bf(hp);
                short lo = f2bf(hp - bf2f(hi));
                hbuf[rb ^ 1][0][r][w * 16 + l] = hi;
                hbuf[rb ^ 1][1][r][w * 16 + l] = lo;
            }
        }
    }
}

// ---------------------------------------------------------------------------
extern "C" void kernel_launch(void* const* d_in, const int* in_sizes, int n_in,
                              void* d_out, int out_size, void* d_ws, size_t ws_size,
                              hipStream_t stream)
{
    const float* X      = (const float*)d_in[0];
    const float* X_last = (const float*)d_in[1];
    const float* W_x    = (const float*)d_in[2];
    const float* b_x    = (const float*)d_in[3];
    const float* W_h    = (const float*)d_in[4];
    const float* b_h    = (const float*)d_in[5];
    const float* W_ih   = (const float*)d_in[6];
    const float* b_ih   = (const float*)d_in[7];
    const float* W_hh   = (const float*)d_in[8];
    const float* b_hh   = (const float*)d_in[9];
    const float* W_attn = (const float*)d_in[10];

    float* ws = (float*)d_ws;
    // layout (floats):
    //   DX : [0, 16777216)              dead after K2
    //   SX : [16777216, 33554432)       dead after K3
    //   G  : [0, 33554432)              written in K4 (over DX+SX)
    //   CM : [33554432, 33685504)
    float* DX = ws;
    float* SX = ws + (size_t)16777216;
    float* Gb = ws;
    float* CM = ws + (size_t)33554432;

    float* Xt   = (float*)d_out;                       // (B,T,F)
    float* Xenc = (float*)d_out + (size_t)16777216;    // (B,T,H)
    float* DH   = Xenc;                                // aliased (see K5)

    k1_preprocess<<<BB, 256, 0, stream>>>(X, X_last, W_x, b_x, W_attn, DX, SX, CM);
    gemm_f32_dh<<<dim3(MM / 64, 1), 256, 0, stream>>>(DX, W_h, b_h, DH, HH);
    k3_softmax<<<MM / 4, 256, 0, stream>>>(SX, CM, X, Xt);
    k4_gemm_bf16<<<dim3(MM / 128, 4), 256, 0, stream>>>(Xt, W_ih, b_ih, b_hh, Gb);
    k5_recurrence_mfma<<<BB / 2, 512, 0, stream>>>(DH, Gb, W_hh, Xenc);
}

// Round 7
// 575.971 us; speedup vs baseline: 1.6801x; 1.2251x over previous
//
#include <hip/hip_runtime.h>
#include <hip/hip_bf16.h>
#include <cmath>

// Problem dims (fixed): B=512, T=128, F=256, H=128, 4H=512, M=B*T=65536
#define BB 512
#define TT 128
#define FF 256
#define HH 128
#define GG 512
#define MM 65536

typedef short bf16x8 __attribute__((ext_vector_type(8)));
typedef float f32x4 __attribute__((ext_vector_type(4)));

__device__ __forceinline__ float sigmf(float x) { return 1.0f / (1.0f + __expf(-x)); }
__device__ __forceinline__ float tanh_fast(float x) {
    return 1.0f - 2.0f / (__expf(2.0f * x) + 1.0f);
}
__device__ __forceinline__ short f2bf(float f) {
    __hip_bfloat16 h = __float2bfloat16(f);   // round-to-nearest-even
    return *reinterpret_cast<short*>(&h);
}
__device__ __forceinline__ float bf2f(short s) {
    unsigned int u = ((unsigned int)(unsigned short)s) << 16;
    return __uint_as_float(u);
}
__device__ __forceinline__ bf16x8 cvt8(const float* p) {
    bf16x8 r;
#pragma unroll
    for (int i = 0; i < 8; ++i) r[i] = f2bf(p[i]);
    return r;
}

// ---------------------------------------------------------------------------
// K1: per (b,f) lane over time: mask, deltaX, X_mean, dx, X_new, Sx cumsum,
// c_mask.  grid: B blocks x F threads.  DX now stored as bf16 (exact:
// deltaX is integer-valued < 256).
// ---------------------------------------------------------------------------
__global__ __launch_bounds__(256) void k1_preprocess(
    const float* __restrict__ X, const float* __restrict__ X_last,
    const float* __restrict__ W_x, const float* __restrict__ b_x,
    const float* __restrict__ W_attn,
    unsigned short* __restrict__ DX, float* __restrict__ SX, float* __restrict__ CM)
{
    const int b = blockIdx.x;
    const int f = threadIdx.x;
    __shared__ float wl[256];               // [wa_x(128) | wa_m(128)]
    wl[f] = W_attn[256 + f];
    __syncthreads();

    const float* xb  = X      + (size_t)b * TT * FF + f;
    const float* xlb = X_last + (size_t)b * TT * FF + f;

    unsigned long long mb0 = 0ull, mb1 = 0ull;
    float sum = 0.f, cnt = 0.f, cm = 0.f;
    for (int t = 0; t < TT; ++t) {
        float x = xb[t * FF];
        bool m = (x != -1.0f);
        if (m) {
            sum += x; cnt += 1.0f;
            if (t < 64) mb0 |= (1ull << t); else mb1 |= (1ull << (t - 64));
        }
        cm += (m ? 1.0f : 0.0f) * wl[128 + t];
    }
    const float mean = (cnt > 0.f) ? (sum / cnt) : 0.f;
    CM[(size_t)b * FF + f] = cm;

    const float wxd = W_x[(size_t)f * FF + f];
    const float bx  = b_x[f];
    unsigned short* dxb = DX + (size_t)b * TT * FF + f;
    float* sxb = SX + (size_t)b * TT * FF + f;

    float d = 0.f, s = 0.f;
    bool mprev = false;
    for (int t = 0; t < TT; ++t) {
        bool m = (t < 64) ? ((mb0 >> t) & 1ull) : ((mb1 >> (t - 64)) & 1ull);
        if (t > 0) d = mprev ? 1.0f : (d + 1.0f);
        mprev = m;
        dxb[t * FF] = (unsigned short)f2bf(d);
        float x   = xb[t * FF];
        float x0  = m ? x : 0.f;
        float dxv = __expf(-fmaxf(fmaf(d, wxd, bx), 0.f));
        float xl  = xlb[t * FF];
        float xnew = m ? x0 : (dxv * xl + (1.0f - dxv) * mean);
        s += xnew * wl[t];
        sxb[t * FF] = s;
    }
}

// ---------------------------------------------------------------------------
// K2: bf16 MFMA GEMM (Dh).  Dh = exp(-relu(DX @ W_h^T + b_h)).
// DX already bf16 (exact integers); W_h split hi+lo (2 MFMA passes) ->
// effectively f32-exact.  BM=128, BN=128(full), BK=64.  256 thr, 2x2 waves.
// Same XOR-swizzled LDS pattern as (verified) K4.
// ---------------------------------------------------------------------------
__global__ __launch_bounds__(256) void k2_gemm_dh_mfma(
    const unsigned short* __restrict__ A,  // DX bf16 (M,256)
    const float* __restrict__ W,           // W_h (128,256) f32
    const float* __restrict__ bias1,       // b_h
    float* __restrict__ C)                 // Dh (M,128) f32
{
    __shared__ short As[128 * 64];    // 16KB
    __shared__ short Bh[128 * 64];    // 16KB (W_h hi)
    __shared__ short Bl[128 * 64];    // 16KB (W_h lo residual)

    const int tid  = threadIdx.x;
    const int lane = tid & 63;
    const int wave = tid >> 6;
    const int wm = wave >> 1, wn = wave & 1;
    const int r0 = blockIdx.x * 128;

    f32x4 acc[4][4] = {};

    for (int kc = 0; kc < 256; kc += 64) {
#pragma unroll
        for (int i = 0; i < 4; ++i) {
            int slot = i * 256 + tid;          // 1024 slots = 128 rows x 8 kgroups
            int row = slot >> 3, kg = slot & 7;
            int byte = (row * 128 + kg * 16) ^ ((row & 7) << 4);
            *(bf16x8*)((char*)As + byte) =
                *(const bf16x8*)&A[(size_t)(r0 + row) * 256 + kc + kg * 8];
            float tmp[8];
            *(float4*)&tmp[0] = *(const float4*)&W[(size_t)row * 256 + kc + kg * 8];
            *(float4*)&tmp[4] = *(const float4*)&W[(size_t)row * 256 + kc + kg * 8 + 4];
            bf16x8 hi, lo;
#pragma unroll
            for (int j = 0; j < 8; ++j) {
                hi[j] = f2bf(tmp[j]);
                lo[j] = f2bf(tmp[j] - bf2f(hi[j]));
            }
            *(bf16x8*)((char*)Bh + byte) = hi;
            *(bf16x8*)((char*)Bl + byte) = lo;
        }
        __syncthreads();

#pragma unroll
        for (int ks = 0; ks < 2; ++ks) {
            bf16x8 af[4], bh[4], bl[4];
#pragma unroll
            for (int mf = 0; mf < 4; ++mf) {
                int row = wm * 64 + mf * 16 + (lane & 15);
                int byte = (row * 128 + ks * 64 + (lane >> 4) * 16) ^ ((row & 7) << 4);
                af[mf] = *(const bf16x8*)((const char*)As + byte);
            }
#pragma unroll
            for (int nf = 0; nf < 4; ++nf) {
                int row = wn * 64 + nf * 16 + (lane & 15);
                int byte = (row * 128 + ks * 64 + (lane >> 4) * 16) ^ ((row & 7) << 4);
                bh[nf] = *(const bf16x8*)((const char*)Bh + byte);
                bl[nf] = *(const bf16x8*)((const char*)Bl + byte);
            }
#pragma unroll
            for (int mf = 0; mf < 4; ++mf)
#pragma unroll
                for (int nf = 0; nf < 4; ++nf) {
                    acc[mf][nf] = __builtin_amdgcn_mfma_f32_16x16x32_bf16(
                        af[mf], bh[nf], acc[mf][nf], 0, 0, 0);
                    acc[mf][nf] = __builtin_amdgcn_mfma_f32_16x16x32_bf16(
                        af[mf], bl[nf], acc[mf][nf], 0, 0, 0);
                }
        }
        __syncthreads();
    }

    float b1[4];
#pragma unroll
    for (int nf = 0; nf < 4; ++nf) b1[nf] = bias1[wn * 64 + nf * 16 + (lane & 15)];
#pragma unroll
    for (int mf = 0; mf < 4; ++mf)
#pragma unroll
        for (int nf = 0; nf < 4; ++nf) {
            int col = wn * 64 + nf * 16 + (lane & 15);
#pragma unroll
            for (int reg = 0; reg < 4; ++reg) {
                int row = r0 + wm * 64 + mf * 16 + (lane >> 4) * 4 + reg;
                C[(size_t)row * HH + col] = __expf(-fmaxf(acc[mf][nf][reg] + b1[nf], 0.f));
            }
        }
}

// ---------------------------------------------------------------------------
// K3: alpha = softmax_f(Sx + c_mask); X_tilde = alpha * X0.  (unchanged)
// ---------------------------------------------------------------------------
__global__ __launch_bounds__(256) void k3_softmax(
    const float* __restrict__ SX, const float* __restrict__ CM,
    const float* __restrict__ X, float* __restrict__ Xt)
{
    const int tid  = threadIdx.x;
    const int lane = tid & 63;
    const int w    = tid >> 6;
    const int r    = blockIdx.x * 4 + w;
    const int b    = r >> 7;

    const float4 sx = *(const float4*)&SX[(size_t)r * FF + lane * 4];
    const float4 cm = *(const float4*)&CM[(size_t)b * FF + lane * 4];
    float s0 = sx.x + cm.x, s1 = sx.y + cm.y, s2 = sx.z + cm.z, s3 = sx.w + cm.w;

    float mx = fmaxf(fmaxf(s0, s1), fmaxf(s2, s3));
#pragma unroll
    for (int o = 32; o > 0; o >>= 1) mx = fmaxf(mx, __shfl_xor(mx, o));
    float e0 = __expf(s0 - mx), e1 = __expf(s1 - mx);
    float e2 = __expf(s2 - mx), e3 = __expf(s3 - mx);
    float sm = e0 + e1 + e2 + e3;
#pragma unroll
    for (int o = 32; o > 0; o >>= 1) sm += __shfl_xor(sm, o);
    float inv = 1.0f / sm;

    const float4 xv = *(const float4*)&X[(size_t)r * FF + lane * 4];
    float4 o4;
    o4.x = ((xv.x != -1.0f) ? xv.x : 0.f) * e0 * inv;
    o4.y = ((xv.y != -1.0f) ? xv.y : 0.f) * e1 * inv;
    o4.z = ((xv.z != -1.0f) ? xv.z : 0.f) * e2 * inv;
    o4.w = ((xv.w != -1.0f) ? xv.w : 0.f) * e3 * inv;
    *(float4*)&Xt[(size_t)r * FF + lane * 4] = o4;
}

// ---------------------------------------------------------------------------
// K4: bf16 MFMA GEMM.  G = Xt(f32->bf16) @ W_ih^T(f32->bf16) + b_ih + b_hh.
// (unchanged from verified Round-6 version)
// ---------------------------------------------------------------------------
__global__ __launch_bounds__(256) void k4_gemm_bf16(
    const float* __restrict__ A,      // Xt (M,256) f32
    const float* __restrict__ W,      // W_ih (512,256) f32
    const float* __restrict__ bias1,  // b_ih
    const float* __restrict__ bias2,  // b_hh
    float* __restrict__ C)            // G (M,512) f32
{
    __shared__ short As[128 * 64];    // 16KB
    __shared__ short Bs[128 * 64];    // 16KB

    const int tid  = threadIdx.x;
    const int lane = tid & 63;
    const int wave = tid >> 6;
    const int wm = wave >> 1, wn = wave & 1;
    const int r0 = blockIdx.x * 128;
    const int c0 = blockIdx.y * 128;

    f32x4 acc[4][4] = {};

    for (int kc = 0; kc < 256; kc += 64) {
#pragma unroll
        for (int i = 0; i < 4; ++i) {
            int slot = i * 256 + tid;
            int row = slot >> 3, kg = slot & 7;
            int byte = (row * 128 + kg * 16) ^ ((row & 7) << 4);
            float tmp[8];
            *(float4*)&tmp[0] = *(const float4*)&A[(size_t)(r0 + row) * 256 + kc + kg * 8];
            *(float4*)&tmp[4] = *(const float4*)&A[(size_t)(r0 + row) * 256 + kc + kg * 8 + 4];
            *(bf16x8*)((char*)As + byte) = cvt8(tmp);
            *(float4*)&tmp[0] = *(const float4*)&W[(size_t)(c0 + row) * 256 + kc + kg * 8];
            *(float4*)&tmp[4] = *(const float4*)&W[(size_t)(c0 + row) * 256 + kc + kg * 8 + 4];
            *(bf16x8*)((char*)Bs + byte) = cvt8(tmp);
        }
        __syncthreads();

#pragma unroll
        for (int ks = 0; ks < 2; ++ks) {
            bf16x8 af[4], bw[4];
#pragma unroll
            for (int mf = 0; mf < 4; ++mf) {
                int row = wm * 64 + mf * 16 + (lane & 15);
                int byte = (row * 128 + ks * 64 + (lane >> 4) * 16) ^ ((row & 7) << 4);
                af[mf] = *(const bf16x8*)((const char*)As + byte);
            }
#pragma unroll
            for (int nf = 0; nf < 4; ++nf) {
                int row = wn * 64 + nf * 16 + (lane & 15);
                int byte = (row * 128 + ks * 64 + (lane >> 4) * 16) ^ ((row & 7) << 4);
                bw[nf] = *(const bf16x8*)((const char*)Bs + byte);
            }
#pragma unroll
            for (int mf = 0; mf < 4; ++mf)
#pragma unroll
                for (int nf = 0; nf < 4; ++nf)
                    acc[mf][nf] = __builtin_amdgcn_mfma_f32_16x16x32_bf16(
                        af[mf], bw[nf], acc[mf][nf], 0, 0, 0);
        }
        __syncthreads();
    }

    float bsum[4];
#pragma unroll
    for (int nf = 0; nf < 4; ++nf) {
        int col = c0 + wn * 64 + nf * 16 + (lane & 15);
        bsum[nf] = bias1[col] + bias2[col];
    }
#pragma unroll
    for (int mf = 0; mf < 4; ++mf)
#pragma unroll
        for (int nf = 0; nf < 4; ++nf) {
            int col = c0 + wn * 64 + nf * 16 + (lane & 15);
#pragma unroll
            for (int reg = 0; reg < 4; ++reg) {
                int row = r0 + wm * 64 + mf * 16 + (lane >> 4) * 4 + reg;
                C[(size_t)row * GG + col] = acc[mf][nf][reg] + bsum[nf];
            }
        }
}

// ---------------------------------------------------------------------------
// K5: sequential recurrence via MFMA.  256 blocks x 512 threads (8 waves),
// 2 batch rows/block.  W_hh in VGPRs as bf16 B-frags; h split hi+lo.
// A rows alternate h0,h1 -> C rows repeat (h0,h1,...) every 4 rows, so
// acc[q][0]/acc[q][1] hold BOTH batch rows in EVERY 16-lane group: the
// epilogue runs on lanes 0-31 (r = (lane>>4)&1) with a register select --
// both rows in one wave-op, no divergent double-work, no shuffles.
// hbuf rows padded 128->160 shorts: rows 0/1 on disjoint bank halves.
// Prefetch via per-lane base pointers + imm offsets.  Dh aliased into Xenc
// region (reads >= 2 steps ahead of writes, same-wave, program-ordered).
// ---------------------------------------------------------------------------
__global__ __launch_bounds__(512) void k5_recurrence_mfma(
    const float* __restrict__ Dh, const float* __restrict__ G,
    const float* __restrict__ W_hh, float* __restrict__ Xenc)
{
    __shared__ short hbuf[2][2][2][160];   // [buf][hi/lo][row][k padded]
    const int tid  = threadIdx.x;
    const int lane = tid & 63;
    const int w    = tid >> 6;             // wave 0..7
    const int b0   = blockIdx.x * 2;
    const int l    = lane & 15;
    const int r    = (lane >> 4) & 1;      // batch-row for this lane group
    const bool st  = (lane < 32);          // lanes 32-63 compute replicas

    // W_hh fragments -> bf16 VGPRs.  B[k][col]: col = q*128+16w+l,
    // k = ks*32 + (lane>>4)*8 + j
    bf16x8 wf[4][4];
#pragma unroll
    for (int q = 0; q < 4; ++q)
#pragma unroll
        for (int ks = 0; ks < 4; ++ks) {
            int gate = q * 128 + w * 16 + l;
            const float* src = &W_hh[(size_t)gate * HH + ks * 32 + (lane >> 4) * 8];
            float tmp[8];
            *(float4*)&tmp[0] = *(const float4*)&src[0];
            *(float4*)&tmp[4] = *(const float4*)&src[4];
            wf[q][ks] = cvt8(tmp);
        }

    for (int i = tid; i < 2 * 2 * 2 * 160; i += 512) ((short*)hbuf)[i] = 0;

    const float* gb = G    + (size_t)(b0 + r) * TT * GG + w * 16 + l;
    const float* db = Dh   + (size_t)(b0 + r) * TT * HH + w * 16 + l;
    float*       xb = Xenc + (size_t)(b0 + r) * TT * HH + w * 16 + l;

    float cst = 0.f;
    float gq0 = gb[0], gq1 = gb[128], gq2 = gb[256], gq3 = gb[384];
    float dnx = db[HH];                    // Dh[t=1]

    for (int t = 0; t < TT; ++t) {
        __syncthreads();                   // orders prev writes vs this read
        const int rb = t & 1;
        f32x4 acc[4] = {};
#pragma unroll
        for (int s = 0; s < 2; ++s)
#pragma unroll
            for (int ks = 0; ks < 4; ++ks) {
                const bf16x8 af =
                    *(const bf16x8*)&hbuf[rb][s][lane & 1][ks * 32 + (lane >> 4) * 8];
#pragma unroll
                for (int q = 0; q < 4; ++q)
                    acc[q] = __builtin_amdgcn_mfma_f32_16x16x32_bf16(af, wf[q][ks], acc[q], 0, 0, 0);
            }

        // issue next-step prefetch (consumed next iteration)
        const int tn  = (t + 1 < TT) ? (t + 1) : (TT - 1);
        const int tn2 = (t + 2 < TT) ? (t + 2) : (TT - 1);
        const float* gp = gb + (size_t)tn * GG;
        float ngq0 = gp[0], ngq1 = gp[128], ngq2 = gp[256], ngq3 = gp[384];
        float ndnx = db[(size_t)tn2 * HH];

        // epilogue: both batch rows in one wave-op (select, no shuffle)
        float gi = (r ? acc[0][1] : acc[0][0]) + gq0;
        float gf = (r ? acc[1][1] : acc[1][0]) + gq1;
        float gg = (r ? acc[2][1] : acc[2][0]) + gq2;
        float go = (r ? acc[3][1] : acc[3][0]) + gq3;
        float c = sigmf(gf) * cst + sigmf(gi) * tanh_fast(gg);
        cst = c;
        float h = sigmf(go) * tanh_fast(c);
        float hp = dnx * h;
        short hhi = f2bf(hp);
        short hlo = f2bf(hp - bf2f(hhi));
        if (st) {
            xb[(size_t)t * HH] = h;
            hbuf[rb ^ 1][0][r][w * 16 + l] = hhi;
            hbuf[rb ^ 1][1][r][w * 16 + l] = hlo;
        }
        gq0 = ngq0; gq1 = ngq1; gq2 = ngq2; gq3 = ngq3;
        dnx = ndnx;
    }
}

// ---------------------------------------------------------------------------
extern "C" void kernel_launch(void* const* d_in, const int* in_sizes, int n_in,
                              void* d_out, int out_size, void* d_ws, size_t ws_size,
                              hipStream_t stream)
{
    const float* X      = (const float*)d_in[0];
    const float* X_last = (const float*)d_in[1];
    const float* W_x    = (const float*)d_in[2];
    const float* b_x    = (const float*)d_in[3];
    const float* W_h    = (const float*)d_in[4];
    const float* b_h    = (const float*)d_in[5];
    const float* W_ih   = (const float*)d_in[6];
    const float* b_ih   = (const float*)d_in[7];
    const float* W_hh   = (const float*)d_in[8];
    const float* b_hh   = (const float*)d_in[9];
    const float* W_attn = (const float*)d_in[10];

    float* ws = (float*)d_ws;
    // layout:
    //   DXbf (ushort): bytes [0, 33,554,432)            dead after K2
    //   SX (f32):      float idx [8,388,608, 25,165,824) dead after K3
    //   G  (f32):      float idx [0, 33,554,432)         written by K4
    //   CM (f32):      float idx [33,554,432, ...)       beyond G
    unsigned short* DXbf = (unsigned short*)ws;
    float* SX = ws + (size_t)8388608;
    float* Gb = ws;
    float* CM = ws + (size_t)33554432;

    float* Xt   = (float*)d_out;                       // (B,T,F)
    float* Xenc = (float*)d_out + (size_t)16777216;    // (B,T,H)
    float* DH   = Xenc;                                // aliased (see K5)

    k1_preprocess<<<BB, 256, 0, stream>>>(X, X_last, W_x, b_x, W_attn, DXbf, SX, CM);
    k2_gemm_dh_mfma<<<MM / 128, 256, 0, stream>>>(DXbf, W_h, b_h, DH);
    k3_softmax<<<MM / 4, 256, 0, stream>>>(SX, CM, X, Xt);
    k4_gemm_bf16<<<dim3(MM / 128, 4), 256, 0, stream>>>(Xt, W_ih, b_ih, b_hh, Gb);
    k5_recurrence_mfma<<<BB / 2, 512, 0, stream>>>(DH, Gb, W_hh, Xenc);
}

// Round 8
// 472.748 us; speedup vs baseline: 2.0470x; 1.2183x over previous
//
#include <hip/hip_runtime.h>
#include <hip/hip_bf16.h>
#include <cmath>

// Problem dims (fixed): B=512, T=128, F=256, H=128, 4H=512, M=B*T=65536
#define BB 512
#define TT 128
#define FF 256
#define HH 128
#define GG 512
#define MM 65536

typedef short bf16x8 __attribute__((ext_vector_type(8)));
typedef float f32x4 __attribute__((ext_vector_type(4)));

__device__ __forceinline__ float sigmf(float x) { return 1.0f / (1.0f + __expf(-x)); }
__device__ __forceinline__ float tanh_fast(float x) {
    return 1.0f - 2.0f / (__expf(2.0f * x) + 1.0f);
}
__device__ __forceinline__ short f2bf(float f) {
    __hip_bfloat16 h = __float2bfloat16(f);   // round-to-nearest-even
    return *reinterpret_cast<short*>(&h);
}
__device__ __forceinline__ float bf2f(short s) {
    unsigned int u = ((unsigned int)(unsigned short)s) << 16;
    return __uint_as_float(u);
}
__device__ __forceinline__ bf16x8 cvt8(const float* p) {
    bf16x8 r;
#pragma unroll
    for (int i = 0; i < 8; ++i) r[i] = f2bf(p[i]);
    return r;
}

// ---------------------------------------------------------------------------
// K1: per (b,f) lane over time.  Round-8 change: explicit load batching for
// memory-level parallelism (was VGPR=12, ~2 loads in flight, latency-bound
// at 1.1 TB/s).  Pass 1: bursts of 16 X loads.  Pass 2: bursts of 8 X +
// 8 X_last loads, then the serial d/cumsum chain on registers.
// ---------------------------------------------------------------------------
__global__ __launch_bounds__(256) void k1_preprocess(
    const float* __restrict__ X, const float* __restrict__ X_last,
    const float* __restrict__ W_x, const float* __restrict__ b_x,
    const float* __restrict__ W_attn,
    unsigned short* __restrict__ DX, float* __restrict__ SX, float* __restrict__ CM)
{
    const int b = blockIdx.x;
    const int f = threadIdx.x;
    __shared__ float wl[256];               // [wa_x(128) | wa_m(128)]
    wl[f] = W_attn[256 + f];
    __syncthreads();

    const float* xb  = X      + (size_t)b * TT * FF + f;
    const float* xlb = X_last + (size_t)b * TT * FF + f;

    // pass 1: mask bits, sum/count, c_mask  (16 loads in flight per burst)
    unsigned long long mb0 = 0ull, mb1 = 0ull;
    float sum = 0.f, cnt = 0.f, cm = 0.f;
    for (int tb = 0; tb < TT; tb += 16) {
        float xs[16];
#pragma unroll
        for (int i = 0; i < 16; ++i) xs[i] = xb[(tb + i) * FF];
#pragma unroll
        for (int i = 0; i < 16; ++i) {
            int t = tb + i;
            bool m = (xs[i] != -1.0f);
            if (m) {
                sum += xs[i]; cnt += 1.0f;
                if (t < 64) mb0 |= (1ull << t); else mb1 |= (1ull << (t - 64));
            }
            cm += (m ? 1.0f : 0.0f) * wl[128 + t];
        }
    }
    const float mean = (cnt > 0.f) ? (sum / cnt) : 0.f;
    CM[(size_t)b * FF + f] = cm;

    const float wxd = W_x[(size_t)f * FF + f];
    const float bx  = b_x[f];
    unsigned short* dxb = DX + (size_t)b * TT * FF + f;
    float* sxb = SX + (size_t)b * TT * FF + f;

    // pass 2: deltaX, X_new, running cumsum  (8+8 loads in flight per burst)
    float d = 0.f, s = 0.f;
    bool mprev = false;
    for (int tb = 0; tb < TT; tb += 8) {
        float xv[8], xlv[8];
#pragma unroll
        for (int i = 0; i < 8; ++i) xv[i]  = xb[(tb + i) * FF];
#pragma unroll
        for (int i = 0; i < 8; ++i) xlv[i] = xlb[(tb + i) * FF];
#pragma unroll
        for (int i = 0; i < 8; ++i) {
            int t = tb + i;
            bool m = (t < 64) ? ((mb0 >> t) & 1ull) : ((mb1 >> (t - 64)) & 1ull);
            if (t > 0) d = mprev ? 1.0f : (d + 1.0f);
            mprev = m;
            dxb[t * FF] = (unsigned short)f2bf(d);
            float x0  = m ? xv[i] : 0.f;
            float dxv = __expf(-fmaxf(fmaf(d, wxd, bx), 0.f));
            float xnew = m ? x0 : (dxv * xlv[i] + (1.0f - dxv) * mean);
            s += xnew * wl[t];
            sxb[t * FF] = s;
        }
    }
}

// ---------------------------------------------------------------------------
// K2: bf16 MFMA GEMM (Dh).  Dh = exp(-relu(DX @ W_h^T + b_h)).
// DX already bf16 (exact integers); W_h split hi+lo (2 MFMA passes) ->
// effectively f32-exact.  BM=128, BN=128(full), BK=64.  256 thr, 2x2 waves.
// (unchanged from verified Round-7 version)
// ---------------------------------------------------------------------------
__global__ __launch_bounds__(256) void k2_gemm_dh_mfma(
    const unsigned short* __restrict__ A,  // DX bf16 (M,256)
    const float* __restrict__ W,           // W_h (128,256) f32
    const float* __restrict__ bias1,       // b_h
    float* __restrict__ C)                 // Dh (M,128) f32
{
    __shared__ short As[128 * 64];    // 16KB
    __shared__ short Bh[128 * 64];    // 16KB (W_h hi)
    __shared__ short Bl[128 * 64];    // 16KB (W_h lo residual)

    const int tid  = threadIdx.x;
    const int lane = tid & 63;
    const int wave = tid >> 6;
    const int wm = wave >> 1, wn = wave & 1;
    const int r0 = blockIdx.x * 128;

    f32x4 acc[4][4] = {};

    for (int kc = 0; kc < 256; kc += 64) {
#pragma unroll
        for (int i = 0; i < 4; ++i) {
            int slot = i * 256 + tid;          // 1024 slots = 128 rows x 8 kgroups
            int row = slot >> 3, kg = slot & 7;
            int byte = (row * 128 + kg * 16) ^ ((row & 7) << 4);
            *(bf16x8*)((char*)As + byte) =
                *(const bf16x8*)&A[(size_t)(r0 + row) * 256 + kc + kg * 8];
            float tmp[8];
            *(float4*)&tmp[0] = *(const float4*)&W[(size_t)row * 256 + kc + kg * 8];
            *(float4*)&tmp[4] = *(const float4*)&W[(size_t)row * 256 + kc + kg * 8 + 4];
            bf16x8 hi, lo;
#pragma unroll
            for (int j = 0; j < 8; ++j) {
                hi[j] = f2bf(tmp[j]);
                lo[j] = f2bf(tmp[j] - bf2f(hi[j]));
            }
            *(bf16x8*)((char*)Bh + byte) = hi;
            *(bf16x8*)((char*)Bl + byte) = lo;
        }
        __syncthreads();

#pragma unroll
        for (int ks = 0; ks < 2; ++ks) {
            bf16x8 af[4], bh[4], bl[4];
#pragma unroll
            for (int mf = 0; mf < 4; ++mf) {
                int row = wm * 64 + mf * 16 + (lane & 15);
                int byte = (row * 128 + ks * 64 + (lane >> 4) * 16) ^ ((row & 7) << 4);
                af[mf] = *(const bf16x8*)((const char*)As + byte);
            }
#pragma unroll
            for (int nf = 0; nf < 4; ++nf) {
                int row = wn * 64 + nf * 16 + (lane & 15);
                int byte = (row * 128 + ks * 64 + (lane >> 4) * 16) ^ ((row & 7) << 4);
                bh[nf] = *(const bf16x8*)((const char*)Bh + byte);
                bl[nf] = *(const bf16x8*)((const char*)Bl + byte);
            }
#pragma unroll
            for (int mf = 0; mf < 4; ++mf)
#pragma unroll
                for (int nf = 0; nf < 4; ++nf) {
                    acc[mf][nf] = __builtin_amdgcn_mfma_f32_16x16x32_bf16(
                        af[mf], bh[nf], acc[mf][nf], 0, 0, 0);
                    acc[mf][nf] = __builtin_amdgcn_mfma_f32_16x16x32_bf16(
                        af[mf], bl[nf], acc[mf][nf], 0, 0, 0);
                }
        }
        __syncthreads();
    }

    float b1[4];
#pragma unroll
    for (int nf = 0; nf < 4; ++nf) b1[nf] = bias1[wn * 64 + nf * 16 + (lane & 15)];
#pragma unroll
    for (int mf = 0; mf < 4; ++mf)
#pragma unroll
        for (int nf = 0; nf < 4; ++nf) {
            int col = wn * 64 + nf * 16 + (lane & 15);
#pragma unroll
            for (int reg = 0; reg < 4; ++reg) {
                int row = r0 + wm * 64 + mf * 16 + (lane >> 4) * 4 + reg;
                C[(size_t)row * HH + col] = __expf(-fmaxf(acc[mf][nf][reg] + b1[nf], 0.f));
            }
        }
}

// ---------------------------------------------------------------------------
// K3: alpha = softmax_f(Sx + c_mask); X_tilde = alpha * X0.  (unchanged)
// ---------------------------------------------------------------------------
__global__ __launch_bounds__(256) void k3_softmax(
    const float* __restrict__ SX, const float* __restrict__ CM,
    const float* __restrict__ X, float* __restrict__ Xt)
{
    const int tid  = threadIdx.x;
    const int lane = tid & 63;
    const int w    = tid >> 6;
    const int r    = blockIdx.x * 4 + w;
    const int b    = r >> 7;

    const float4 sx = *(const float4*)&SX[(size_t)r * FF + lane * 4];
    const float4 cm = *(const float4*)&CM[(size_t)b * FF + lane * 4];
    float s0 = sx.x + cm.x, s1 = sx.y + cm.y, s2 = sx.z + cm.z, s3 = sx.w + cm.w;

    float mx = fmaxf(fmaxf(s0, s1), fmaxf(s2, s3));
#pragma unroll
    for (int o = 32; o > 0; o >>= 1) mx = fmaxf(mx, __shfl_xor(mx, o));
    float e0 = __expf(s0 - mx), e1 = __expf(s1 - mx);
    float e2 = __expf(s2 - mx), e3 = __expf(s3 - mx);
    float sm = e0 + e1 + e2 + e3;
#pragma unroll
    for (int o = 32; o > 0; o >>= 1) sm += __shfl_xor(sm, o);
    float inv = 1.0f / sm;

    const float4 xv = *(const float4*)&X[(size_t)r * FF + lane * 4];
    float4 o4;
    o4.x = ((xv.x != -1.0f) ? xv.x : 0.f) * e0 * inv;
    o4.y = ((xv.y != -1.0f) ? xv.y : 0.f) * e1 * inv;
    o4.z = ((xv.z != -1.0f) ? xv.z : 0.f) * e2 * inv;
    o4.w = ((xv.w != -1.0f) ? xv.w : 0.f) * e3 * inv;
    *(float4*)&Xt[(size_t)r * FF + lane * 4] = o4;
}

// ---------------------------------------------------------------------------
// K4: bf16 MFMA GEMM.  G = Xt(f32->bf16) @ W_ih^T(f32->bf16) + b_ih + b_hh.
// (unchanged from verified Round-6 version)
// ---------------------------------------------------------------------------
__global__ __launch_bounds__(256) void k4_gemm_bf16(
    const float* __restrict__ A,      // Xt (M,256) f32
    const float* __restrict__ W,      // W_ih (512,256) f32
    const float* __restrict__ bias1,  // b_ih
    const float* __restrict__ bias2,  // b_hh
    float* __restrict__ C)            // G (M,512) f32
{
    __shared__ short As[128 * 64];    // 16KB
    __shared__ short Bs[128 * 64];    // 16KB

    const int tid  = threadIdx.x;
    const int lane = tid & 63;
    const int wave = tid >> 6;
    const int wm = wave >> 1, wn = wave & 1;
    const int r0 = blockIdx.x * 128;
    const int c0 = blockIdx.y * 128;

    f32x4 acc[4][4] = {};

    for (int kc = 0; kc < 256; kc += 64) {
#pragma unroll
        for (int i = 0; i < 4; ++i) {
            int slot = i * 256 + tid;
            int row = slot >> 3, kg = slot & 7;
            int byte = (row * 128 + kg * 16) ^ ((row & 7) << 4);
            float tmp[8];
            *(float4*)&tmp[0] = *(const float4*)&A[(size_t)(r0 + row) * 256 + kc + kg * 8];
            *(float4*)&tmp[4] = *(const float4*)&A[(size_t)(r0 + row) * 256 + kc + kg * 8 + 4];
            *(bf16x8*)((char*)As + byte) = cvt8(tmp);
            *(float4*)&tmp[0] = *(const float4*)&W[(size_t)(c0 + row) * 256 + kc + kg * 8];
            *(float4*)&tmp[4] = *(const float4*)&W[(size_t)(c0 + row) * 256 + kc + kg * 8 + 4];
            *(bf16x8*)((char*)Bs + byte) = cvt8(tmp);
        }
        __syncthreads();

#pragma unroll
        for (int ks = 0; ks < 2; ++ks) {
            bf16x8 af[4], bw[4];
#pragma unroll
            for (int mf = 0; mf < 4; ++mf) {
                int row = wm * 64 + mf * 16 + (lane & 15);
                int byte = (row * 128 + ks * 64 + (lane >> 4) * 16) ^ ((row & 7) << 4);
                af[mf] = *(const bf16x8*)((const char*)As + byte);
            }
#pragma unroll
            for (int nf = 0; nf < 4; ++nf) {
                int row = wn * 64 + nf * 16 + (lane & 15);
                int byte = (row * 128 + ks * 64 + (lane >> 4) * 16) ^ ((row & 7) << 4);
                bw[nf] = *(const bf16x8*)((const char*)Bs + byte);
            }
#pragma unroll
            for (int mf = 0; mf < 4; ++mf)
#pragma unroll
                for (int nf = 0; nf < 4; ++nf)
                    acc[mf][nf] = __builtin_amdgcn_mfma_f32_16x16x32_bf16(
                        af[mf], bw[nf], acc[mf][nf], 0, 0, 0);
        }
        __syncthreads();
    }

    float bsum[4];
#pragma unroll
    for (int nf = 0; nf < 4; ++nf) {
        int col = c0 + wn * 64 + nf * 16 + (lane & 15);
        bsum[nf] = bias1[col] + bias2[col];
    }
#pragma unroll
    for (int mf = 0; mf < 4; ++mf)
#pragma unroll
        for (int nf = 0; nf < 4; ++nf) {
            int col = c0 + wn * 64 + nf * 16 + (lane & 15);
#pragma unroll
            for (int reg = 0; reg < 4; ++reg) {
                int row = r0 + wm * 64 + mf * 16 + (lane >> 4) * 4 + reg;
                C[(size_t)row * GG + col] = acc[mf][nf][reg] + bsum[nf];
            }
        }
}

// ---------------------------------------------------------------------------
// K5: sequential recurrence via MFMA.  (unchanged from verified Round-7)
// ---------------------------------------------------------------------------
__global__ __launch_bounds__(512) void k5_recurrence_mfma(
    const float* __restrict__ Dh, const float* __restrict__ G,
    const float* __restrict__ W_hh, float* __restrict__ Xenc)
{
    __shared__ short hbuf[2][2][2][160];   // [buf][hi/lo][row][k padded]
    const int tid  = threadIdx.x;
    const int lane = tid & 63;
    const int w    = tid >> 6;             // wave 0..7
    const int b0   = blockIdx.x * 2;
    const int l    = lane & 15;
    const int r    = (lane >> 4) & 1;      // batch-row for this lane group
    const bool st  = (lane < 32);          // lanes 32-63 compute replicas

    bf16x8 wf[4][4];
#pragma unroll
    for (int q = 0; q < 4; ++q)
#pragma unroll
        for (int ks = 0; ks < 4; ++ks) {
            int gate = q * 128 + w * 16 + l;
            const float* src = &W_hh[(size_t)gate * HH + ks * 32 + (lane >> 4) * 8];
            float tmp[8];
            *(float4*)&tmp[0] = *(const float4*)&src[0];
            *(float4*)&tmp[4] = *(const float4*)&src[4];
            wf[q][ks] = cvt8(tmp);
        }

    for (int i = tid; i < 2 * 2 * 2 * 160; i += 512) ((short*)hbuf)[i] = 0;

    const float* gb = G    + (size_t)(b0 + r) * TT * GG + w * 16 + l;
    const float* db = Dh   + (size_t)(b0 + r) * TT * HH + w * 16 + l;
    float*       xb = Xenc + (size_t)(b0 + r) * TT * HH + w * 16 + l;

    float cst = 0.f;
    float gq0 = gb[0], gq1 = gb[128], gq2 = gb[256], gq3 = gb[384];
    float dnx = db[HH];                    // Dh[t=1]

    for (int t = 0; t < TT; ++t) {
        __syncthreads();                   // orders prev writes vs this read
        const int rb = t & 1;
        f32x4 acc[4] = {};
#pragma unroll
        for (int s = 0; s < 2; ++s)
#pragma unroll
            for (int ks = 0; ks < 4; ++ks) {
                const bf16x8 af =
                    *(const bf16x8*)&hbuf[rb][s][lane & 1][ks * 32 + (lane >> 4) * 8];
#pragma unroll
                for (int q = 0; q < 4; ++q)
                    acc[q] = __builtin_amdgcn_mfma_f32_16x16x32_bf16(af, wf[q][ks], acc[q], 0, 0, 0);
            }

        const int tn  = (t + 1 < TT) ? (t + 1) : (TT - 1);
        const int tn2 = (t + 2 < TT) ? (t + 2) : (TT - 1);
        const float* gp = gb + (size_t)tn * GG;
        float ngq0 = gp[0], ngq1 = gp[128], ngq2 = gp[256], ngq3 = gp[384];
        float ndnx = db[(size_t)tn2 * HH];

        float gi = (r ? acc[0][1] : acc[0][0]) + gq0;
        float gf = (r ? acc[1][1] : acc[1][0]) + gq1;
        float gg = (r ? acc[2][1] : acc[2][0]) + gq2;
        float go = (r ? acc[3][1] : acc[3][0]) + gq3;
        float c = sigmf(gf) * cst + sigmf(gi) * tanh_fast(gg);
        cst = c;
        float h = sigmf(go) * tanh_fast(c);
        float hp = dnx * h;
        short hhi = f2bf(hp);
        short hlo = f2bf(hp - bf2f(hhi));
        if (st) {
            xb[(size_t)t * HH] = h;
            hbuf[rb ^ 1][0][r][w * 16 + l] = hhi;
            hbuf[rb ^ 1][1][r][w * 16 + l] = hlo;
        }
        gq0 = ngq0; gq1 = ngq1; gq2 = ngq2; gq3 = ngq3;
        dnx = ndnx;
    }
}

// ---------------------------------------------------------------------------
extern "C" void kernel_launch(void* const* d_in, const int* in_sizes, int n_in,
                              void* d_out, int out_size, void* d_ws, size_t ws_size,
                              hipStream_t stream)
{
    const float* X      = (const float*)d_in[0];
    const float* X_last = (const float*)d_in[1];
    const float* W_x    = (const float*)d_in[2];
    const float* b_x    = (const float*)d_in[3];
    const float* W_h    = (const float*)d_in[4];
    const float* b_h    = (const float*)d_in[5];
    const float* W_ih   = (const float*)d_in[6];
    const float* b_ih   = (const float*)d_in[7];
    const float* W_hh   = (const float*)d_in[8];
    const float* b_hh   = (const float*)d_in[9];
    const float* W_attn = (const float*)d_in[10];

    float* ws = (float*)d_ws;
    // layout:
    //   DXbf (ushort): bytes [0, 33,554,432)            dead after K2
    //   SX (f32):      float idx [8,388,608, 25,165,824) dead after K3
    //   G  (f32):      float idx [0, 33,554,432)         written by K4
    //   CM (f32):      float idx [33,554,432, ...)       beyond G
    unsigned short* DXbf = (unsigned short*)ws;
    float* SX = ws + (size_t)8388608;
    float* Gb = ws;
    float* CM = ws + (size_t)33554432;

    float* Xt   = (float*)d_out;                       // (B,T,F)
    float* Xenc = (float*)d_out + (size_t)16777216;    // (B,T,H)
    float* DH   = Xenc;                                // aliased (see K5)

    k1_preprocess<<<BB, 256, 0, stream>>>(X, X_last, W_x, b_x, W_attn, DXbf, SX, CM);
    k2_gemm_dh_mfma<<<MM / 128, 256, 0, stream>>>(DXbf, W_h, b_h, DH);
    k3_softmax<<<MM / 4, 256, 0, stream>>>(SX, CM, X, Xt);
    k4_gemm_bf16<<<dim3(MM / 128, 4), 256, 0, stream>>>(Xt, W_ih, b_ih, b_hh, Gb);
    k5_recurrence_mfma<<<BB / 2, 512, 0, stream>>>(DH, Gb, W_hh, Xenc);
}